// Round 1
// baseline (103.682 us; speedup 1.0000x reference)
//
#include <hip/hip_runtime.h>
#include <cstdint>

typedef __bf16 v8bf __attribute__((ext_vector_type(8)));
typedef float f32x4 __attribute__((ext_vector_type(4)));
typedef uint16_t u16;

__device__ __forceinline__ u16 f2bf(float f) {
  uint32_t u = __float_as_uint(f);
  u += 0x7FFFu + ((u >> 16) & 1u);   // round-to-nearest-even
  return (u16)(u >> 16);
}

#define AS1(p) ((__attribute__((address_space(1))) void*)(p))
#define AS3(p) ((__attribute__((address_space(3))) void*)(p))

// ---------------- K1: 1/||x_row|| ----------------
__global__ __launch_bounds__(256) void k_rownorm(const float* __restrict__ x,
                                                 float* __restrict__ rnorm) {
  const int row = blockIdx.x;
  const float* p = x + (size_t)row * 1024;
  float s = 0.f;
  for (int c = threadIdx.x; c < 1024; c += 256) { float v = p[c]; s += v * v; }
#pragma unroll
  for (int off = 32; off > 0; off >>= 1) s += __shfl_down(s, off, 64);
  __shared__ float ps[4];
  if ((threadIdx.x & 63) == 0) ps[threadIdx.x >> 6] = s;
  __syncthreads();
  if (threadIdx.x == 0) {
    float t = ps[0] + ps[1] + ps[2] + ps[3];
    rnorm[row] = 1.0f / sqrtf(t);  // norms ~32, eps clamp never binds
  }
}

// ---------------- K2: build Y (bf16, row-major), Yt, Xt (bf16, [1024][8192]) ----------------
__global__ __launch_bounds__(256) void k_build(const float* __restrict__ x,
                                               const float* __restrict__ rnorm,
                                               u16* __restrict__ Y,
                                               u16* __restrict__ Yt,
                                               u16* __restrict__ Xt) {
  __shared__ float tile[64][65];
  __shared__ float rn[64];
  const int d0 = blockIdx.x * 64;   // 0..1023
  const int i0 = blockIdx.y * 64;   // 0..8191
  const int tr = threadIdx.x >> 6;  // 0..3
  const int tc = threadIdx.x & 63;
#pragma unroll
  for (int it = 0; it < 16; ++it) {
    int r = it * 4 + tr;
    tile[r][tc] = x[(size_t)(i0 + r) * 1024 + d0 + tc];
  }
  if (threadIdx.x < 64) rn[threadIdx.x] = rnorm[i0 + threadIdx.x];
  __syncthreads();
#pragma unroll
  for (int it = 0; it < 16; ++it) {
    int r = it * 4 + tr;
    Y[(size_t)(i0 + r) * 1024 + d0 + tc] = f2bf(tile[r][tc] * rn[r]);
  }
#pragma unroll
  for (int it = 0; it < 16; ++it) {
    int rr = it * 4 + tr;            // d within tile
    float v = tile[tc][rr];          // x[i0+tc][d0+rr]
    size_t o = (size_t)(d0 + rr) * 8192 + i0 + tc;
    Xt[o] = f2bf(v);
    Yt[o] = f2bf(v * rn[tc]);
  }
}

// ---------------- GEMM: C = A[M][K] * B[N][K]^T, bf16 in, f32 acc ----------------
// 128x128 tile, 4 waves (2x2), each wave 64x64 = 4x4 frags of 16x16x32 MFMA.
// EPI==0: plain f32 store (split-K partial).  EPI==1: sigmoid(acc + x*rn*zdiag).
template <int EPI>
__global__ __launch_bounds__(256, 2) void k_gemm_bt(
    const u16* __restrict__ A, const u16* __restrict__ B, float* __restrict__ C,
    int N, int K, int k_len, size_t c_split_stride,
    const float* __restrict__ Xf, const float* __restrict__ rnorm,
    const float* __restrict__ zdiag) {
  __shared__ u16 lA[128 * 32] __attribute__((aligned(16)));
  __shared__ u16 lB[128 * 32] __attribute__((aligned(16)));
  const int tid = threadIdx.x;
  const int wave = tid >> 6;
  const int lane = tid & 63;
  const int wm = wave >> 1, wn = wave & 1;
  const int m0 = blockIdx.y * 128;
  const int n0 = blockIdx.x * 128;
  const int k_start = blockIdx.z * k_len;
  C += (size_t)blockIdx.z * c_split_stride;

  f32x4 acc[4][4] = {};

  const int frow = lane & 15;
  const int fkb = (lane >> 4) * 16;          // byte offset of 8-elem k-chunk
  const int so = wave * 2048 + lane * 16;    // staging byte offset (lane part implicit in HW)

  for (int kt = 0; kt < k_len; kt += 32) {
    const int kk = k_start + kt;
#pragma unroll
    for (int j = 0; j < 2; ++j) {
      const int o = so + j * 1024;           // linear byte offset in [128][32] u16 tile
      const int row = o >> 6;
      const int colb = o & 63;
      const u16* gA = A + (size_t)(m0 + row) * K + kk + (colb >> 1);
      const u16* gB = B + (size_t)(n0 + row) * K + kk + (colb >> 1);
      // LDS dest is wave-uniform base; lanes write base + lane*16 (HW semantics)
      __builtin_amdgcn_global_load_lds(AS1(gA), AS3((char*)lA + wave * 2048 + j * 1024), 16, 0, 0);
      __builtin_amdgcn_global_load_lds(AS1(gB), AS3((char*)lB + wave * 2048 + j * 1024), 16, 0, 0);
    }
    __syncthreads();
    v8bf af[4], bfr[4];
#pragma unroll
    for (int i = 0; i < 4; ++i) {
      af[i]  = *(const v8bf*)((const char*)lA + (wm * 64 + i * 16 + frow) * 64 + fkb);
      bfr[i] = *(const v8bf*)((const char*)lB + (wn * 64 + i * 16 + frow) * 64 + fkb);
    }
#pragma unroll
    for (int mi = 0; mi < 4; ++mi)
#pragma unroll
      for (int ni = 0; ni < 4; ++ni)
        acc[mi][ni] = __builtin_amdgcn_mfma_f32_16x16x32_bf16(af[mi], bfr[ni], acc[mi][ni], 0, 0, 0);
    __syncthreads();
  }

  // C/D layout (verified): col = lane&15, row = (lane>>4)*4 + reg
  const int crow = (lane >> 4) * 4;
  const int ccol = lane & 15;
#pragma unroll
  for (int mi = 0; mi < 4; ++mi) {
#pragma unroll
    for (int ni = 0; ni < 4; ++ni) {
      const int row = m0 + wm * 64 + mi * 16 + crow;
      const int col = n0 + wn * 64 + ni * 16 + ccol;
#pragma unroll
      for (int r = 0; r < 4; ++r) {
        const size_t o = (size_t)(row + r) * N + col;
        float v = acc[mi][ni][r];
        if (EPI == 0) {
          C[o] = v;
        } else {
          float z = v + Xf[o] * rnorm[row + r] * zdiag[col];  // exact diag term
          C[o] = 1.0f / (1.0f + __expf(-z));
        }
      }
    }
  }
}

// ---------------- K4: reduce split-K partials -> bf16 Z (diag zeroed, saved f32) ----------------
__global__ __launch_bounds__(256) void k_reduce(const float* __restrict__ part,
                                                u16* __restrict__ Ztb,
                                                float* __restrict__ zdiag) {
  const int idx = blockIdx.x * 256 + threadIdx.x;  // over 1024*1024
  float s = 0.f;
#pragma unroll
  for (int p = 0; p < 8; ++p) s += part[idx + (size_t)p * (1 << 20)];
  const int m = idx >> 10, n = idx & 1023;
  if (m == n) { zdiag[m] = s; Ztb[idx] = 0; }
  else Ztb[idx] = f2bf(s);
}

extern "C" void kernel_launch(void* const* d_in, const int* in_sizes, int n_in,
                              void* d_out, int out_size, void* d_ws, size_t ws_size,
                              hipStream_t stream) {
  const float* x = (const float*)d_in[0];
  float* out = (float*)d_out;
  char* ws = (char*)d_ws;

  // ws layout (~50.1 MB): rnorm | Y | Yt | Xt | Ztb | zdiag
  float* rnorm = (float*)ws;                                   // 32 KB
  u16* Y    = (u16*)(ws + (1u << 16));                         // 16 MB
  u16* Yt   = (u16*)(ws + (1u << 16) + (16u << 20));           // 16 MB
  u16* Xt   = (u16*)(ws + (1u << 16) + (32u << 20));           // 16 MB
  u16* Ztb  = (u16*)(ws + (1u << 16) + (48u << 20));           // 2 MB
  float* zdiag = (float*)(ws + (1u << 16) + (50u << 20));      // 4 KB
  float* part = out;  // 8 x 4 MB split-K partials live in d_out (exactly 32 MB), consumed before final write

  k_rownorm<<<8192, 256, 0, stream>>>(x, rnorm);
  k_build<<<dim3(16, 128), 256, 0, stream>>>(x, rnorm, Y, Yt, Xt);
  // Zt[d][k] = sum_i Xt[d][i] * Yt[k][i], K=8192, split-K=8
  k_gemm_bt<0><<<dim3(8, 8, 8), 256, 0, stream>>>(Xt, Yt, part, 1024, 8192, 1024,
                                                  (size_t)1 << 20, nullptr, nullptr, nullptr);
  k_reduce<<<4096, 256, 0, stream>>>(part, Ztb, zdiag);
  // out[i][d] = sigmoid( sum_k Y[i][k]*Zt[d][k] + x[i][d]*rn[i]*zdiag[d] )
  k_gemm_bt<1><<<dim3(8, 64, 1), 256, 0, stream>>>(Y, Ztb, out, 1024, 1024, 1024,
                                                   0, x, rnorm, zdiag);
}

// Round 2
// 97.974 us; speedup vs baseline: 1.0583x; 1.0583x over previous
//
#include <hip/hip_runtime.h>
#include <cstdint>

typedef __bf16 v8bf __attribute__((ext_vector_type(8)));
typedef float f32x4 __attribute__((ext_vector_type(4)));
typedef uint16_t u16;

__device__ __forceinline__ u16 f2bf(float f) {
  uint32_t u = __float_as_uint(f);
  u += 0x7FFFu + ((u >> 16) & 1u);   // round-to-nearest-even
  return (u16)(u >> 16);
}

#define AS1(p) ((__attribute__((address_space(1))) void*)(p))
#define AS3(p) ((__attribute__((address_space(3))) void*)(p))

// ---------------- K1: 1/||x_row|| ----------------
__global__ __launch_bounds__(256) void k_rownorm(const float* __restrict__ x,
                                                 float* __restrict__ rnorm) {
  const int row = blockIdx.x;
  const float* p = x + (size_t)row * 1024;
  float s = 0.f;
  for (int c = threadIdx.x; c < 1024; c += 256) { float v = p[c]; s += v * v; }
#pragma unroll
  for (int off = 32; off > 0; off >>= 1) s += __shfl_down(s, off, 64);
  __shared__ float ps[4];
  if ((threadIdx.x & 63) == 0) ps[threadIdx.x >> 6] = s;
  __syncthreads();
  if (threadIdx.x == 0) {
    float t = ps[0] + ps[1] + ps[2] + ps[3];
    rnorm[row] = 1.0f / sqrtf(t);  // norms ~32, eps clamp never binds
  }
}

// ---------------- K2: build Y (bf16, row-major), Yt, Xt (bf16, [1024][8192]) ----------------
__global__ __launch_bounds__(256) void k_build(const float* __restrict__ x,
                                               const float* __restrict__ rnorm,
                                               u16* __restrict__ Y,
                                               u16* __restrict__ Yt,
                                               u16* __restrict__ Xt) {
  __shared__ float tile[64][65];
  __shared__ float rn[64];
  const int d0 = blockIdx.x * 64;   // 0..1023
  const int i0 = blockIdx.y * 64;   // 0..8191
  const int tr = threadIdx.x >> 6;  // 0..3
  const int tc = threadIdx.x & 63;
#pragma unroll
  for (int it = 0; it < 16; ++it) {
    int r = it * 4 + tr;
    tile[r][tc] = x[(size_t)(i0 + r) * 1024 + d0 + tc];
  }
  if (threadIdx.x < 64) rn[threadIdx.x] = rnorm[i0 + threadIdx.x];
  __syncthreads();
#pragma unroll
  for (int it = 0; it < 16; ++it) {
    int r = it * 4 + tr;
    Y[(size_t)(i0 + r) * 1024 + d0 + tc] = f2bf(tile[r][tc] * rn[r]);
  }
#pragma unroll
  for (int it = 0; it < 16; ++it) {
    int rr = it * 4 + tr;            // d within tile
    float v = tile[tc][rr];          // x[i0+tc][d0+rr]
    size_t o = (size_t)(d0 + rr) * 8192 + i0 + tc;
    Xt[o] = f2bf(v);
    Yt[o] = f2bf(v * rn[tc]);
  }
}

// ---------------- GEMM: C = A[M][K] * B[N][K]^T, bf16 in, f32 acc ----------------
// 128x128 tile, 4 waves (2x2), each wave 64x64 = 4x4 frags of 16x16x32 MFMA.
// 3-buffer LDS ring, depth-2 prefetch, counted vmcnt(4) (4 global_load_lds
// per wave per tile), raw s_barrier — loads stay in flight across barriers.
// EPI==0: plain f32 store (split-K partial).  EPI==1: sigmoid(acc + x*rn*zdiag).
template <int EPI>
__global__ __launch_bounds__(256, 2) void k_gemm_bt(
    const u16* __restrict__ A, const u16* __restrict__ B, float* __restrict__ C,
    int N, int K, int k_len, size_t c_split_stride,
    const float* __restrict__ Xf, const float* __restrict__ rnorm,
    const float* __restrict__ zdiag) {
  // per buffer: A tile [128][32] u16 (8KB) at +0, B tile at +8192
  __shared__ char lds[3][16384] __attribute__((aligned(16)));
  const int tid = threadIdx.x;
  const int wave = tid >> 6;
  const int lane = tid & 63;
  const int wm = wave >> 1, wn = wave & 1;
  const int m0 = blockIdx.y * 128;
  const int n0 = blockIdx.x * 128;
  const int k_start = blockIdx.z * k_len;
  C += (size_t)blockIdx.z * c_split_stride;

  f32x4 acc[4][4] = {};

  const int frow = lane & 15;
  const int fkb = (lane >> 4) * 16;          // byte offset of 8-elem k-chunk

  // staging geometry: per operand 8KB/tile; wave w covers [w*2048, w*2048+2048)
  // as two 1KB issues; lane l writes LDS base + l*16 (HW: uniform base + lane*16)
  const int o0 = wave * 2048 + lane * 16;
  const int s_row0 = o0 >> 6;                // tile row of this lane, issue 0
  const int s_ce = (o0 & 63) >> 1;           // k-element within row
  const int s_row1 = (o0 + 1024) >> 6;

  const u16* gA0 = A + (size_t)(m0 + s_row0) * K + k_start + s_ce;
  const u16* gA1 = A + (size_t)(m0 + s_row1) * K + k_start + s_ce;
  const u16* gB0 = B + (size_t)(n0 + s_row0) * K + k_start + s_ce;
  const u16* gB1 = B + (size_t)(n0 + s_row1) * K + k_start + s_ce;

#define STAGE(buf, kt)                                                          \
  do {                                                                          \
    const int _kk = (kt) * 32;                                                  \
    __builtin_amdgcn_global_load_lds(AS1(gA0 + _kk), AS3(&lds[(buf)][wave * 2048]), 16, 0, 0);          \
    __builtin_amdgcn_global_load_lds(AS1(gA1 + _kk), AS3(&lds[(buf)][wave * 2048 + 1024]), 16, 0, 0);   \
    __builtin_amdgcn_global_load_lds(AS1(gB0 + _kk), AS3(&lds[(buf)][8192 + wave * 2048]), 16, 0, 0);   \
    __builtin_amdgcn_global_load_lds(AS1(gB1 + _kk), AS3(&lds[(buf)][8192 + wave * 2048 + 1024]), 16, 0, 0); \
  } while (0)

#define COMPUTE(buf)                                                            \
  do {                                                                          \
    v8bf af[4], bfr[4];                                                         \
    const char* baseA = lds[(buf)] + (wm * 64 + frow) * 64 + fkb;               \
    const char* baseB = lds[(buf)] + 8192 + (wn * 64 + frow) * 64 + fkb;        \
    _Pragma("unroll")                                                           \
    for (int i = 0; i < 4; ++i) {                                               \
      af[i] = *(const v8bf*)(baseA + i * 1024);                                 \
      bfr[i] = *(const v8bf*)(baseB + i * 1024);                                \
    }                                                                           \
    _Pragma("unroll")                                                           \
    for (int mi = 0; mi < 4; ++mi)                                              \
      _Pragma("unroll")                                                         \
      for (int ni = 0; ni < 4; ++ni)                                            \
        acc[mi][ni] = __builtin_amdgcn_mfma_f32_16x16x32_bf16(af[mi], bfr[ni], acc[mi][ni], 0, 0, 0); \
  } while (0)

  const int nt = k_len >> 5;  // 32 for both GEMMs
  STAGE(0, 0);
  STAGE(1, 1);
  int cur = 0;
  for (int t = 0; t < nt - 1; ++t) {
    asm volatile("s_waitcnt vmcnt(4)" ::: "memory");  // stage(t) done, stage(t+1) in flight
    __builtin_amdgcn_s_barrier();
    const int nxt2 = (cur + 2 >= 3) ? cur - 1 : cur + 2;
    if (t + 2 < nt) STAGE(nxt2, t + 2);
    COMPUTE(cur);
    cur = (cur + 1 >= 3) ? cur - 2 : cur + 1;
  }
  asm volatile("s_waitcnt vmcnt(0)" ::: "memory");
  __builtin_amdgcn_s_barrier();
  COMPUTE(cur);
#undef STAGE
#undef COMPUTE

  // C/D layout (verified): col = lane&15, row = (lane>>4)*4 + reg
  const int crow = (lane >> 4) * 4;
  const int ccol = lane & 15;
#pragma unroll
  for (int mi = 0; mi < 4; ++mi) {
#pragma unroll
    for (int ni = 0; ni < 4; ++ni) {
      const int row = m0 + wm * 64 + mi * 16 + crow;
      const int col = n0 + wn * 64 + ni * 16 + ccol;
#pragma unroll
      for (int r = 0; r < 4; ++r) {
        const size_t o = (size_t)(row + r) * N + col;
        float v = acc[mi][ni][r];
        if (EPI == 0) {
          C[o] = v;
        } else {
          float z = v + Xf[o] * rnorm[row + r] * zdiag[col];  // exact diag term
          C[o] = 1.0f / (1.0f + __expf(-z));
        }
      }
    }
  }
}

// ---------------- K4: reduce split-K partials -> bf16 Z (diag zeroed, saved f32) ----------------
__global__ __launch_bounds__(256) void k_reduce(const float* __restrict__ part,
                                                u16* __restrict__ Ztb,
                                                float* __restrict__ zdiag) {
  const int idx = blockIdx.x * 256 + threadIdx.x;  // over 1024*1024
  float s = 0.f;
#pragma unroll
  for (int p = 0; p < 8; ++p) s += part[idx + (size_t)p * (1 << 20)];
  const int m = idx >> 10, n = idx & 1023;
  if (m == n) { zdiag[m] = s; Ztb[idx] = 0; }
  else Ztb[idx] = f2bf(s);
}

extern "C" void kernel_launch(void* const* d_in, const int* in_sizes, int n_in,
                              void* d_out, int out_size, void* d_ws, size_t ws_size,
                              hipStream_t stream) {
  const float* x = (const float*)d_in[0];
  float* out = (float*)d_out;
  char* ws = (char*)d_ws;

  // ws layout (~50.1 MB): rnorm | Y | Yt | Xt | Ztb | zdiag
  float* rnorm = (float*)ws;                                   // 32 KB
  u16* Y    = (u16*)(ws + (1u << 16));                         // 16 MB
  u16* Yt   = (u16*)(ws + (1u << 16) + (16u << 20));           // 16 MB
  u16* Xt   = (u16*)(ws + (1u << 16) + (32u << 20));           // 16 MB
  u16* Ztb  = (u16*)(ws + (1u << 16) + (48u << 20));           // 2 MB
  float* zdiag = (float*)(ws + (1u << 16) + (50u << 20));      // 4 KB
  float* part = out;  // 8 x 4 MB split-K partials live in d_out (exactly 32 MB), consumed before final write

  k_rownorm<<<8192, 256, 0, stream>>>(x, rnorm);
  k_build<<<dim3(16, 128), 256, 0, stream>>>(x, rnorm, Y, Yt, Xt);
  // Zt[d][k] = sum_i Xt[d][i] * Yt[k][i], K=8192, split-K=8
  k_gemm_bt<0><<<dim3(8, 8, 8), 256, 0, stream>>>(Xt, Yt, part, 1024, 8192, 1024,
                                                  (size_t)1 << 20, nullptr, nullptr, nullptr);
  k_reduce<<<4096, 256, 0, stream>>>(part, Ztb, zdiag);
  // out[i][d] = sigmoid( sum_k Y[i][k]*Zt[d][k] + x[i][d]*rn[i]*zdiag[d] )
  k_gemm_bt<1><<<dim3(8, 64, 1), 256, 0, stream>>>(Y, Ztb, out, 1024, 1024, 1024,
                                                   0, x, rnorm, zdiag);
}